// Round 6
// baseline (194.184 us; speedup 1.0000x reference)
//
#include <hip/hip_runtime.h>

#define CDIM 256
#define HW   1024
#define NPIX 65536
#define KDIM 1024
#define TAU  0.5f
#define RB   4
#define SWZ(c) (((c) & 31) ^ (((c) >> 3) & 24))

using bf16x8 = __attribute__((ext_vector_type(8))) short;
using f32x4  = __attribute__((ext_vector_type(4))) float;
typedef unsigned int u32;

static __device__ __forceinline__ unsigned short f2bf(float v) {
    union { float f; unsigned u; } a; a.f = v;
    unsigned u = a.u;
    u += 0x7fffu + ((u >> 16) & 1u);   // RTN
    return (unsigned short)(u >> 16);
}

static __device__ __forceinline__ void gload_lds16(const void* g, void* s) {
    __builtin_amdgcn_global_load_lds(
        (const __attribute__((address_space(1))) u32*)g,
        (__attribute__((address_space(3))) u32*)s,
        16, 0, 0);
}

// -------- ee[k] = sum_c embed[c][k]^2 (exact fp32) --------
__global__ void ee_kernel(const float* __restrict__ embed, float* __restrict__ ee) {
    int k = blockIdx.x * 256 + threadIdx.x;
    float s = 0.f;
#pragma unroll 8
    for (int c = 0; c < CDIM; ++c) {
        float v = embed[c * KDIM + k];
        s += v * v;
    }
    ee[k] = s;
}

// -------- embedT[k][c] = embed[c][k] (fp32 transpose, 32x32 LDS tiles) --------
__global__ void transpose_e(const float* __restrict__ embed, float* __restrict__ embedT) {
    __shared__ float tl[32][33];
    const int t = threadIdx.x;
    const int j = t & 31, r = t >> 5;          // j: 0..31, r: 0..7
    const int k0 = (blockIdx.x & 31) * 32;
    const int c0 = (blockIdx.x >> 5) * 32;
#pragma unroll
    for (int rr = 0; rr < 4; ++rr) {
        int c = r * 4 + rr;
        tl[c][j] = embed[(size_t)(c0 + c) * KDIM + k0 + j];
    }
    __syncthreads();
#pragma unroll
    for (int rr = 0; rr < 4; ++rr) {
        int k = r * 4 + rr;
        embedT[(size_t)(k0 + k) * CDIM + c0 + j] = tl[j][k];
    }
}

// -------- bf16(-2*embed) in MFMA B-fragment order, chunk-contiguous --------
__global__ void prep_e(const float* __restrict__ embed, short* __restrict__ e_hi) {
    int tid = blockIdx.x * 256 + threadIdx.x;   // 32768
    int l  = tid & 63;
    int f  = tid >> 6;            // 0..511
    int nf = f & 3;
    int ks = (f >> 2) & 7;
    int nh = (f >> 5) & 1;
    int nt = f >> 6;
    int n  = nt * 128 + (nh * 4 + nf) * 16 + (l & 15);
    int c0 = ks * 32 + (l >> 4) * 8;
    bf16x8 h8;
#pragma unroll
    for (int j = 0; j < 8; ++j)
        h8[j] = (short)f2bf(-2.0f * embed[(c0 + j) * KDIM + n]);
    *(bf16x8*)&e_hi[(size_t)tid * 8] = h8;
}

// -------- main: bf16 MFMA screen, K-split halves, per-half (min,idx,min2) --------
__launch_bounds__(256)
__global__ void vq_gemm(const float* __restrict__ x, const short* __restrict__ e_hi,
                        const float* __restrict__ ee,
                        float* __restrict__ hv1, float* __restrict__ hv2,
                        int* __restrict__ hidx) {
    __shared__ short Bs[2][16384];   // 2 x 32 KB chunks
    const int t  = threadIdx.x;
    const int l  = t & 63;
    const int w  = t >> 6;
    const int lr = l & 15;
    const int lg = l >> 4;
    const int tile = blockIdx.x & 255;
    const int half = blockIdx.x >> 8;           // 0 or 1
    const int ch0  = half * 8;
    const int px0 = tile * 256 + w * 64;        // wave's 64 pixels
    const int b   = px0 >> 10;
    const int p0  = px0 & 1023;
    const float* xb = x + (size_t)b * CDIM * HW;

    // prologue: stage first chunk (overlaps the A-load below)
    {
        const char* src = (const char*)e_hi + (size_t)ch0 * 32768 + w * 8192 + l * 16;
        char* dst = (char*)&Bs[0][0] + w * 8192;
#pragma unroll
        for (int i = 0; i < 8; ++i)
            gload_lds16(src + i * 1024, dst + i * 1024);
    }

    // ---- load + convert A fragments (64 px x 256 ch -> 32 frags) ----
    bf16x8 a[4][8];
#pragma unroll
    for (int mf = 0; mf < 4; ++mf) {
#pragma unroll
        for (int ks = 0; ks < 8; ++ks) {
            const float* p = xb + (size_t)(ks * 32 + lg * 8) * HW + p0 + mf * 16 + lr;
            float v[8];
#pragma unroll
            for (int j = 0; j < 8; ++j) v[j] = p[(size_t)j * HW];
#pragma unroll
            for (int j = 0; j < 8; ++j) a[mf][ks][j] = (short)f2bf(v[j]);
        }
    }

    float minv[16], min2v[16];
    int   mini[16];
#pragma unroll
    for (int r = 0; r < 16; ++r) { minv[r] = 3.4e38f; min2v[r] = 3.4e38f; mini[r] = 0; }

    __syncthreads();   // chunk 0 staged (barrier drains vmcnt)

    for (int cc = 0; cc < 8; ++cc) {
        const int cur = cc & 1;
        if (cc < 7) {   // issue next-chunk stage before compute
            const char* src = (const char*)e_hi + (size_t)(ch0 + cc + 1) * 32768 + w * 8192 + l * 16;
            char* dst = (char*)&Bs[cur ^ 1][0] + w * 8192;
#pragma unroll
            for (int i = 0; i < 8; ++i)
                gload_lds16(src + i * 1024, dst + i * 1024);
        }

        f32x4 acc[4][4];
#pragma unroll
        for (int mf = 0; mf < 4; ++mf)
#pragma unroll
            for (int nf = 0; nf < 4; ++nf)
                acc[mf][nf] = (f32x4){0.f, 0.f, 0.f, 0.f};

#pragma unroll
        for (int ks = 0; ks < 8; ++ks) {
#pragma unroll
            for (int nf = 0; nf < 4; ++nf) {
                bf16x8 bh = *(const bf16x8*)&Bs[cur][((ks * 4 + nf) * 64 + l) * 8];
#pragma unroll
                for (int mf = 0; mf < 4; ++mf)
                    acc[mf][nf] = __builtin_amdgcn_mfma_f32_16x16x32_bf16(a[mf][ks], bh, acc[mf][nf], 0, 0, 0);
            }
        }

        // fold chunk into running (min, argmin, second-min)
#pragma unroll
        for (int nf = 0; nf < 4; ++nf) {
            const int kg = (ch0 + cc) * 64 + nf * 16 + lr;
            const float eev = ee[kg];
#pragma unroll
            for (int mf = 0; mf < 4; ++mf)
#pragma unroll
                for (int j = 0; j < 4; ++j) {
                    const int r = mf * 4 + j;
                    float m = acc[mf][nf][j] + eev;
                    bool lt = m < minv[r];
                    float sec = lt ? minv[r] : m;
                    minv[r] = lt ? m : minv[r];
                    mini[r] = lt ? kg : mini[r];
                    min2v[r] = fminf(min2v[r], sec);
                }
        }
        __syncthreads();   // drains stage vmcnt + protects buffer swap
    }

    // ---- reduce across the 16 lanes sharing each pixel row ----
#pragma unroll
    for (int r = 0; r < 16; ++r) {
        float v1 = minv[r]; int i1 = mini[r]; float v2 = min2v[r];
#pragma unroll
        for (int mask = 1; mask < 16; mask <<= 1) {
            float ov1 = __shfl_xor(v1, mask, 64);
            int   oi1 = __shfl_xor(i1, mask, 64);
            float ov2 = __shfl_xor(v2, mask, 64);
            float vmax = fmaxf(v1, ov1);
            v2 = fminf(fminf(v2, ov2), vmax);
            bool take = (ov1 < v1) || (ov1 == v1 && oi1 < i1);
            v1 = take ? ov1 : v1;
            i1 = take ? oi1 : i1;
        }
        if (lr == 0) {
            int px = px0 + (r >> 2) * 16 + lg * 4 + (r & 3);
            int o = half * NPIX + px;
            hv1[o] = v1; hv2[o] = v2; hidx[o] = i1;
        }
    }
}

// -------- merge the two K-halves, write idx, flag near-ties --------
__global__ void merge_halves(const float* __restrict__ hv1, const float* __restrict__ hv2,
                             const int* __restrict__ hidx, int* __restrict__ idx_out,
                             int* __restrict__ worklist, int* __restrict__ wcount) {
    int px = blockIdx.x * 256 + threadIdx.x;
    float va = hv1[px],        vb = hv1[NPIX + px];
    float sa = hv2[px],        sb = hv2[NPIX + px];
    int   ia = hidx[px],       ib = hidx[NPIX + px];
    bool aw = va <= vb;            // tie -> half 0 (lower indices)
    float v1 = aw ? va : vb;
    int   i1 = aw ? ia : ib;
    float v2 = fminf(aw ? sa : sb, aw ? vb : va);
    idx_out[px] = i1;
    if (v2 - v1 < TAU) {
        int pos = atomicAdd(wcount, 1);
        worklist[pos] = px;
    }
}

// -------- exact fp32 rescore: RB px/block, thread t owns codes 4t..4t+3 --------
__launch_bounds__(256)
__global__ void vq_rescue(const float* __restrict__ x, const float* __restrict__ embed,
                          const float* __restrict__ ee,
                          const int* __restrict__ worklist, const int* __restrict__ wcount,
                          int* __restrict__ idx_out) {
    __shared__ float xs[RB][CDIM];
    __shared__ int   pxs[RB];
    __shared__ float redv[4][RB];
    __shared__ int   redi[4][RB];
    const int t  = threadIdx.x;
    const int wv = t >> 6, ln = t & 63;
    const int cnt = *wcount;
    for (int base = blockIdx.x * RB; base < cnt; base += gridDim.x * RB) {
        const int nb = min(RB, cnt - base);
        __syncthreads();
        if (t < RB) pxs[t] = worklist[base + (t < nb ? t : nb - 1)];
        __syncthreads();
#pragma unroll
        for (int i = 0; i < RB; ++i) {
            int gn = pxs[i];
            xs[i][t] = x[(size_t)(gn >> 10) * CDIM * HW + (size_t)t * HW + (gn & 1023)];
        }
        __syncthreads();

        float4 acc[RB];
#pragma unroll
        for (int i = 0; i < RB; ++i) acc[i] = make_float4(0.f, 0.f, 0.f, 0.f);
#pragma unroll 4
        for (int c = 0; c < CDIM; ++c) {
            float4 ev = *(const float4*)&embed[c * KDIM + t * 4];
#pragma unroll
            for (int i = 0; i < RB; ++i) {
                float xv = xs[i][c];
                acc[i].x = fmaf(xv, ev.x, acc[i].x);
                acc[i].y = fmaf(xv, ev.y, acc[i].y);
                acc[i].z = fmaf(xv, ev.z, acc[i].z);
                acc[i].w = fmaf(xv, ev.w, acc[i].w);
            }
        }
        const float4 eev = *(const float4*)&ee[t * 4];
#pragma unroll
        for (int i = 0; i < RB; ++i) {
            float d0 = fmaf(-2.f, acc[i].x, eev.x);
            float d1 = fmaf(-2.f, acc[i].y, eev.y);
            float d2 = fmaf(-2.f, acc[i].z, eev.z);
            float d3 = fmaf(-2.f, acc[i].w, eev.w);
            float v = d0; int ix = t * 4;
            if (d1 < v) { v = d1; ix = t * 4 + 1; }
            if (d2 < v) { v = d2; ix = t * 4 + 2; }
            if (d3 < v) { v = d3; ix = t * 4 + 3; }
#pragma unroll
            for (int mask = 1; mask < 64; mask <<= 1) {
                float ov = __shfl_xor(v, mask, 64);
                int   oi = __shfl_xor(ix, mask, 64);
                bool take = (ov < v) || (ov == v && oi < ix);
                v = take ? ov : v; ix = take ? oi : ix;
            }
            if (ln == 0) { redv[wv][i] = v; redi[wv][i] = ix; }
        }
        __syncthreads();
        if (t < nb) {
            float fv = redv[0][t]; int fi = redi[0][t];
#pragma unroll
            for (int q = 1; q < 4; ++q) {
                float v = redv[q][t]; int ix = redi[q][t];
                if (v < fv || (v == fv && ix < fi)) { fv = v; fi = ix; }
            }
            idx_out[pxs[t]] = fi;
        }
    }
}

// -------- epilogue: 128 px/block in 2 LDS passes; idx snapshot BEFORE overwrite --------
__launch_bounds__(256)
__global__ void vq_epilogue(const float* __restrict__ x, const float* __restrict__ embed,
                            const float* __restrict__ embedT, int useT,
                            const int* __restrict__ idx_in, float* __restrict__ out_q,
                            float* __restrict__ out_idx, float* __restrict__ partials) {
    __shared__ float q[16384];          // [c][px] with XOR swizzle, 64 KB
    __shared__ int   idxs[128];
    __shared__ float lred[4];
    const int t = threadIdx.x;
    const int w = t >> 6, l = t & 63;
    const int n0 = blockIdx.x * 128;
    const int b  = n0 >> 10;

    // snapshot indices into LDS, THEN overwrite the region with float values
    if (t < 128) idxs[t] = idx_in[n0 + t];
    __syncthreads();
    if (t < 128) out_idx[n0 + t] = (float)idxs[t];

    const int j  = t >> 2;              // pixel 0..63 within pass
    const int qd = t & 3;               // channel quarter
    float lsum = 0.f;

#pragma unroll
    for (int pass = 0; pass < 2; ++pass) {
        // phase A: 4 threads per pixel stage its codebook row
        const int myidx = idxs[pass * 64 + j];
        if (useT) {
            const float4* src4 = (const float4*)embedT + (size_t)myidx * 64;
#pragma unroll
            for (int i = 0; i < 16; ++i) {
                float4 v = src4[qd * 16 + i];
                int c = qd * 64 + i * 4;
                q[(c + 0) * 64 + (j ^ SWZ(c + 0))] = v.x;
                q[(c + 1) * 64 + (j ^ SWZ(c + 1))] = v.y;
                q[(c + 2) * 64 + (j ^ SWZ(c + 2))] = v.z;
                q[(c + 3) * 64 + (j ^ SWZ(c + 3))] = v.w;
            }
        } else {
#pragma unroll 4
            for (int i = 0; i < 64; ++i) {
                int c = qd * 64 + i;
                q[c * 64 + (j ^ SWZ(c))] = embed[(size_t)c * KDIM + myidx];
            }
        }
        __syncthreads();

        // phase B: wave w covers channels [w*64, w*64+64), lanes = pixels (coalesced)
        const int p0 = (n0 & 1023) + pass * 64;
        const size_t xbase = (size_t)b * CDIM * HW + p0;
#pragma unroll 8
        for (int ci = 0; ci < 64; ++ci) {
            int c = w * 64 + ci;
            float qv = q[c * 64 + (l ^ SWZ(c))];
            float xv = x[xbase + (size_t)c * HW + l];
            out_q[xbase + (size_t)c * HW + l] = qv;
            float d = qv - xv;
            lsum = fmaf(d, d, lsum);
        }
        __syncthreads();   // protect q before next pass overwrites
    }

#pragma unroll
    for (int off = 32; off > 0; off >>= 1)
        lsum += __shfl_down(lsum, off, 64);
    if (l == 0) lred[w] = lsum;
    __syncthreads();
    if (t == 0)
        partials[blockIdx.x] = (lred[0] + lred[1]) + (lred[2] + lred[3]);
}

__global__ void loss_kernel(const float* __restrict__ partials, float* __restrict__ out_loss) {
    __shared__ float s[256];
    s[threadIdx.x] = partials[threadIdx.x] + partials[threadIdx.x + 256];
    __syncthreads();
    for (int off = 128; off > 0; off >>= 1) {
        if (threadIdx.x < off) s[threadIdx.x] += s[threadIdx.x + off];
        __syncthreads();
    }
    if (threadIdx.x == 0)
        out_loss[0] = 1.25f * s[0] / 16777216.0f;
}

extern "C" void kernel_launch(void* const* d_in, const int* in_sizes, int n_in,
                              void* d_out, int out_size, void* d_ws, size_t ws_size,
                              hipStream_t stream) {
    const float* x     = (const float*)d_in[0];
    const float* embed = (const float*)d_in[1];
    float* out_q    = (float*)d_out;
    float* out_loss = out_q + (size_t)NPIX * CDIM;
    float* out_idx  = out_loss + 1;
    int*   idx_i32  = (int*)out_idx;

    // scratch inside out_q region (all consumed before epilogue writes)
    short* e_hi     = (short*)out_q;                  // 512 KB
    int*   worklist = (int*)(out_q + 131072);         // 256 KB
    float* hv1      = out_q + 196608;                 // 2 x 64K floats
    float* hv2      = out_q + 327680;
    int*   hidx     = (int*)(out_q + 458752);

    // d_ws: proven-safe 6.4 KB budget; embedT only behind ws_size guard
    float* ws       = (float*)d_ws;
    float* ee       = ws;                             // 1024 floats
    int*   wcount   = (int*)(ws + 1024);              // 64 floats pad
    float* partials = ws + 1088;                      // 512 floats -> 6400 B total
    float* embedT   = ws + 1600;                      // 262144 floats (1 MB), guarded
    int useT = (ws_size >= (size_t)(1600 + 262144) * sizeof(float)) ? 1 : 0;

    ee_kernel<<<KDIM / 256, 256, 0, stream>>>(embed, ee);
    if (useT) transpose_e<<<256, 256, 0, stream>>>(embed, embedT);
    prep_e<<<128, 256, 0, stream>>>(embed, e_hi);
    hipMemsetAsync(wcount, 0, 4, stream);
    vq_gemm<<<512, 256, 0, stream>>>(x, e_hi, ee, hv1, hv2, hidx);
    merge_halves<<<NPIX / 256, 256, 0, stream>>>(hv1, hv2, hidx, idx_i32, worklist, wcount);
    vq_rescue<<<1024, 256, 0, stream>>>(x, embed, ee, worklist, wcount, idx_i32);
    vq_epilogue<<<NPIX / 128, 256, 0, stream>>>(x, embed, useT ? embedT : embed, useT,
                                                idx_i32, out_q, out_idx, partials);
    loss_kernel<<<1, 256, 0, stream>>>(partials, out_loss);
}

// Round 7
// 185.948 us; speedup vs baseline: 1.0443x; 1.0443x over previous
//
#include <hip/hip_runtime.h>

#define CDIM 256
#define HW   1024
#define NPIX 65536
#define KDIM 1024
#define TAU  0.5f
#define RB   4
#define SWZ(c) (((c) & 31) ^ (((c) >> 3) & 24))

using bf16x8 = __attribute__((ext_vector_type(8))) short;
using f32x4  = __attribute__((ext_vector_type(4))) float;
typedef unsigned int u32;

static __device__ __forceinline__ unsigned short f2bf(float v) {
    union { float f; unsigned u; } a; a.f = v;
    unsigned u = a.u;
    u += 0x7fffu + ((u >> 16) & 1u);   // RTN
    return (unsigned short)(u >> 16);
}

static __device__ __forceinline__ void gload_lds16(const void* g, void* s) {
    __builtin_amdgcn_global_load_lds(
        (const __attribute__((address_space(1))) u32*)g,
        (__attribute__((address_space(3))) u32*)s,
        16, 0, 0);
}

// -------- ee[k] = sum_c embed[c][k]^2 (exact fp32) --------
__global__ void ee_kernel(const float* __restrict__ embed, float* __restrict__ ee) {
    int k = blockIdx.x * 256 + threadIdx.x;
    float s = 0.f;
#pragma unroll 8
    for (int c = 0; c < CDIM; ++c) {
        float v = embed[c * KDIM + k];
        s += v * v;
    }
    ee[k] = s;
}

// -------- embedT[k][c] = embed[c][k] (fp32 transpose, 32x32 LDS tiles) --------
__global__ void transpose_e(const float* __restrict__ embed, float* __restrict__ embedT) {
    __shared__ float tl[32][33];
    const int t = threadIdx.x;
    const int j = t & 31, r = t >> 5;
    const int k0 = (blockIdx.x & 31) * 32;
    const int c0 = (blockIdx.x >> 5) * 32;
#pragma unroll
    for (int rr = 0; rr < 4; ++rr) {
        int c = r * 4 + rr;
        tl[c][j] = embed[(size_t)(c0 + c) * KDIM + k0 + j];
    }
    __syncthreads();
#pragma unroll
    for (int rr = 0; rr < 4; ++rr) {
        int k = r * 4 + rr;
        embedT[(size_t)(k0 + k) * CDIM + c0 + j] = tl[j][k];
    }
}

// -------- bf16(-2*embed) in MFMA B-fragment order, chunk-contiguous --------
// frag f = ((nt*2+nh)*8 + ks)*4 + nf; lane l elem j:
//   B[k = ks*32 + (l>>4)*8 + j][n = nt*128 + (nh*4+nf)*16 + (l&15)]
__global__ void prep_e(const float* __restrict__ embed, short* __restrict__ e_hi) {
    int tid = blockIdx.x * 256 + threadIdx.x;   // 32768
    int l  = tid & 63;
    int f  = tid >> 6;            // 0..511
    int nf = f & 3;
    int ks = (f >> 2) & 7;
    int nh = (f >> 5) & 1;
    int nt = f >> 6;
    int n  = nt * 128 + (nh * 4 + nf) * 16 + (l & 15);
    int c0 = ks * 32 + (l >> 4) * 8;
    bf16x8 h8;
#pragma unroll
    for (int j = 0; j < 8; ++j)
        h8[j] = (short)f2bf(-2.0f * embed[(c0 + j) * KDIM + n]);
    *(bf16x8*)&e_hi[(size_t)tid * 8] = h8;
}

// -------- main: bf16 MFMA screen; 8 stages of 128 codes, 2x64KB LDS dbuf --------
__launch_bounds__(256, 1)
__global__ void vq_gemm(const float* __restrict__ x, const short* __restrict__ e_hi,
                        const float* __restrict__ ee, int* __restrict__ idx_out,
                        int* __restrict__ worklist, int* __restrict__ wcount) {
    __shared__ short Bs[2][32768];   // 2 x 64 KB
    const int t  = threadIdx.x;
    const int l  = t & 63;
    const int w  = t >> 6;
    const int lr = l & 15;
    const int lg = l >> 4;
    const int px0 = blockIdx.x * 256 + w * 64;   // wave's 64 pixels
    const int b   = px0 >> 10;
    const int p0  = px0 & 1023;
    const float* xb = x + (size_t)b * CDIM * HW;

    // issue stage 0 (64 KB = codes 0..127): 16 gload_lds per thread
    {
        const char* src = (const char*)e_hi + w * 1024 + l * 16;
        char* dst = (char*)&Bs[0][0] + w * 1024;
#pragma unroll
        for (int i = 0; i < 16; ++i)
            gload_lds16(src + i * 4096, dst + i * 4096);
    }

    // ---- load + convert A fragments (64 px x 256 ch -> 32 frags), overlaps stage 0 ----
    bf16x8 a[4][8];
#pragma unroll
    for (int mf = 0; mf < 4; ++mf) {
#pragma unroll
        for (int ks = 0; ks < 8; ++ks) {
            const float* p = xb + (size_t)(ks * 32 + lg * 8) * HW + p0 + mf * 16 + lr;
            float v[8];
#pragma unroll
            for (int j = 0; j < 8; ++j) v[j] = p[(size_t)j * HW];
#pragma unroll
            for (int j = 0; j < 8; ++j) a[mf][ks][j] = (short)f2bf(v[j]);
        }
    }

    float minv[16], min2v[16];
    int   mini[16];
#pragma unroll
    for (int r = 0; r < 16; ++r) { minv[r] = 3.4e38f; min2v[r] = 3.4e38f; mini[r] = 0; }

    __syncthreads();   // stage 0 landed

    for (int s = 0; s < 8; ++s) {
        const int cur = s & 1;
        if (s < 7) {   // issue next stage into other buffer before computing current
            const char* src = (const char*)e_hi + (size_t)(s + 1) * 65536 + w * 1024 + l * 16;
            char* dst = (char*)&Bs[cur ^ 1][0] + w * 1024;
#pragma unroll
            for (int i = 0; i < 16; ++i)
                gload_lds16(src + i * 4096, dst + i * 4096);
        }

        // compute the 2 x 64-code groups of this stage (no barriers inside)
#pragma unroll
        for (int g = 0; g < 2; ++g) {
            f32x4 acc[4][4];
#pragma unroll
            for (int mf = 0; mf < 4; ++mf)
#pragma unroll
                for (int nf = 0; nf < 4; ++nf)
                    acc[mf][nf] = (f32x4){0.f, 0.f, 0.f, 0.f};

#pragma unroll
            for (int ks = 0; ks < 8; ++ks) {
#pragma unroll
                for (int nf = 0; nf < 4; ++nf) {
                    bf16x8 bh = *(const bf16x8*)&Bs[cur][(((g * 8 + ks) * 4 + nf) * 64 + l) * 8];
#pragma unroll
                    for (int mf = 0; mf < 4; ++mf)
                        acc[mf][nf] = __builtin_amdgcn_mfma_f32_16x16x32_bf16(a[mf][ks], bh, acc[mf][nf], 0, 0, 0);
                }
            }

            // fold group into running (min, argmin, second-min)
#pragma unroll
            for (int nf = 0; nf < 4; ++nf) {
                const int kg = (s * 2 + g) * 64 + nf * 16 + lr;
                const float eev = ee[kg];
#pragma unroll
                for (int mf = 0; mf < 4; ++mf)
#pragma unroll
                    for (int j = 0; j < 4; ++j) {
                        const int r = mf * 4 + j;
                        float m = acc[mf][nf][j] + eev;
                        bool lt = m < minv[r];
                        float sec = lt ? minv[r] : m;
                        minv[r] = lt ? m : minv[r];
                        mini[r] = lt ? kg : mini[r];
                        min2v[r] = fminf(min2v[r], sec);
                    }
            }
        }
        __syncthreads();   // next stage landed (had full compute to finish) + buffer swap
    }

    // ---- reduce across the 16 lanes sharing each pixel row ----
#pragma unroll
    for (int r = 0; r < 16; ++r) {
        float v1 = minv[r]; int i1 = mini[r]; float v2 = min2v[r];
#pragma unroll
        for (int mask = 1; mask < 16; mask <<= 1) {
            float ov1 = __shfl_xor(v1, mask, 64);
            int   oi1 = __shfl_xor(i1, mask, 64);
            float ov2 = __shfl_xor(v2, mask, 64);
            float vmax = fmaxf(v1, ov1);
            v2 = fminf(fminf(v2, ov2), vmax);
            bool take = (ov1 < v1) || (ov1 == v1 && oi1 < i1);
            v1 = take ? ov1 : v1;
            i1 = take ? oi1 : i1;
        }
        if (lr == 0) {
            int px = px0 + (r >> 2) * 16 + lg * 4 + (r & 3);
            idx_out[px] = i1;
            if (v2 - v1 < TAU) {
                int pos = atomicAdd(wcount, 1);
                worklist[pos] = px;
            }
        }
    }
}

// -------- exact fp32 rescore: RB px/block, thread t owns codes 4t..4t+3 --------
__launch_bounds__(256)
__global__ void vq_rescue(const float* __restrict__ x, const float* __restrict__ embed,
                          const float* __restrict__ ee,
                          const int* __restrict__ worklist, const int* __restrict__ wcount,
                          int* __restrict__ idx_out) {
    __shared__ float xs[RB][CDIM];
    __shared__ int   pxs[RB];
    __shared__ float redv[4][RB];
    __shared__ int   redi[4][RB];
    const int t  = threadIdx.x;
    const int wv = t >> 6, ln = t & 63;
    const int cnt = *wcount;
    for (int base = blockIdx.x * RB; base < cnt; base += gridDim.x * RB) {
        const int nb = min(RB, cnt - base);
        __syncthreads();
        if (t < RB) pxs[t] = worklist[base + (t < nb ? t : nb - 1)];
        __syncthreads();
#pragma unroll
        for (int i = 0; i < RB; ++i) {
            int gn = pxs[i];
            xs[i][t] = x[(size_t)(gn >> 10) * CDIM * HW + (size_t)t * HW + (gn & 1023)];
        }
        __syncthreads();

        float4 acc[RB];
#pragma unroll
        for (int i = 0; i < RB; ++i) acc[i] = make_float4(0.f, 0.f, 0.f, 0.f);
#pragma unroll 4
        for (int c = 0; c < CDIM; ++c) {
            float4 ev = *(const float4*)&embed[c * KDIM + t * 4];
#pragma unroll
            for (int i = 0; i < RB; ++i) {
                float xv = xs[i][c];
                acc[i].x = fmaf(xv, ev.x, acc[i].x);
                acc[i].y = fmaf(xv, ev.y, acc[i].y);
                acc[i].z = fmaf(xv, ev.z, acc[i].z);
                acc[i].w = fmaf(xv, ev.w, acc[i].w);
            }
        }
        const float4 eev = *(const float4*)&ee[t * 4];
#pragma unroll
        for (int i = 0; i < RB; ++i) {
            float d0 = fmaf(-2.f, acc[i].x, eev.x);
            float d1 = fmaf(-2.f, acc[i].y, eev.y);
            float d2 = fmaf(-2.f, acc[i].z, eev.z);
            float d3 = fmaf(-2.f, acc[i].w, eev.w);
            float v = d0; int ix = t * 4;
            if (d1 < v) { v = d1; ix = t * 4 + 1; }
            if (d2 < v) { v = d2; ix = t * 4 + 2; }
            if (d3 < v) { v = d3; ix = t * 4 + 3; }
#pragma unroll
            for (int mask = 1; mask < 64; mask <<= 1) {
                float ov = __shfl_xor(v, mask, 64);
                int   oi = __shfl_xor(ix, mask, 64);
                bool take = (ov < v) || (ov == v && oi < ix);
                v = take ? ov : v; ix = take ? oi : ix;
            }
            if (ln == 0) { redv[wv][i] = v; redi[wv][i] = ix; }
        }
        __syncthreads();
        if (t < nb) {
            float fv = redv[0][t]; int fi = redi[0][t];
#pragma unroll
            for (int q = 1; q < 4; ++q) {
                float v = redv[q][t]; int ix = redi[q][t];
                if (v < fv || (v == fv && ix < fi)) { fv = v; fi = ix; }
            }
            idx_out[pxs[t]] = fi;
        }
    }
}

// -------- epilogue: 128 px/block in 2 LDS passes; idx snapshot BEFORE overwrite --------
__launch_bounds__(256)
__global__ void vq_epilogue(const float* __restrict__ x, const float* __restrict__ embed,
                            const float* __restrict__ embedT, int useT,
                            const int* __restrict__ idx_in, float* __restrict__ out_q,
                            float* __restrict__ out_idx, float* __restrict__ partials) {
    __shared__ float q[16384];
    __shared__ int   idxs[128];
    __shared__ float lred[4];
    const int t = threadIdx.x;
    const int w = t >> 6, l = t & 63;
    const int n0 = blockIdx.x * 128;
    const int b  = n0 >> 10;

    if (t < 128) idxs[t] = idx_in[n0 + t];
    __syncthreads();
    if (t < 128) out_idx[n0 + t] = (float)idxs[t];

    const int j  = t >> 2;
    const int qd = t & 3;
    float lsum = 0.f;

#pragma unroll
    for (int pass = 0; pass < 2; ++pass) {
        const int myidx = idxs[pass * 64 + j];
        if (useT) {
            const float4* src4 = (const float4*)embedT + (size_t)myidx * 64;
#pragma unroll
            for (int i = 0; i < 16; ++i) {
                float4 v = src4[qd * 16 + i];
                int c = qd * 64 + i * 4;
                q[(c + 0) * 64 + (j ^ SWZ(c + 0))] = v.x;
                q[(c + 1) * 64 + (j ^ SWZ(c + 1))] = v.y;
                q[(c + 2) * 64 + (j ^ SWZ(c + 2))] = v.z;
                q[(c + 3) * 64 + (j ^ SWZ(c + 3))] = v.w;
            }
        } else {
#pragma unroll 4
            for (int i = 0; i < 64; ++i) {
                int c = qd * 64 + i;
                q[c * 64 + (j ^ SWZ(c))] = embed[(size_t)c * KDIM + myidx];
            }
        }
        __syncthreads();

        const int p0 = (n0 & 1023) + pass * 64;
        const size_t xbase = (size_t)b * CDIM * HW + p0;
#pragma unroll 8
        for (int ci = 0; ci < 64; ++ci) {
            int c = w * 64 + ci;
            float qv = q[c * 64 + (l ^ SWZ(c))];
            float xv = x[xbase + (size_t)c * HW + l];
            out_q[xbase + (size_t)c * HW + l] = qv;
            float d = qv - xv;
            lsum = fmaf(d, d, lsum);
        }
        __syncthreads();
    }

#pragma unroll
    for (int off = 32; off > 0; off >>= 1)
        lsum += __shfl_down(lsum, off, 64);
    if (l == 0) lred[w] = lsum;
    __syncthreads();
    if (t == 0)
        partials[blockIdx.x] = (lred[0] + lred[1]) + (lred[2] + lred[3]);
}

__global__ void loss_kernel(const float* __restrict__ partials, float* __restrict__ out_loss) {
    __shared__ float s[256];
    s[threadIdx.x] = partials[threadIdx.x] + partials[threadIdx.x + 256];
    __syncthreads();
    for (int off = 128; off > 0; off >>= 1) {
        if (threadIdx.x < off) s[threadIdx.x] += s[threadIdx.x + off];
        __syncthreads();
    }
    if (threadIdx.x == 0)
        out_loss[0] = 1.25f * s[0] / 16777216.0f;
}

extern "C" void kernel_launch(void* const* d_in, const int* in_sizes, int n_in,
                              void* d_out, int out_size, void* d_ws, size_t ws_size,
                              hipStream_t stream) {
    const float* x     = (const float*)d_in[0];
    const float* embed = (const float*)d_in[1];
    float* out_q    = (float*)d_out;
    float* out_loss = out_q + (size_t)NPIX * CDIM;
    float* out_idx  = out_loss + 1;
    int*   idx_i32  = (int*)out_idx;

    // scratch inside out_q region (all consumed before epilogue writes)
    short* e_hi     = (short*)out_q;                  // 512 KB
    int*   worklist = (int*)(out_q + 131072);         // 256 KB

    // d_ws: proven-safe 6.4 KB budget; embedT only behind ws_size guard
    float* ws       = (float*)d_ws;
    float* ee       = ws;                             // 1024 floats
    int*   wcount   = (int*)(ws + 1024);              // 64 floats pad
    float* partials = ws + 1088;                      // 512 floats -> 6400 B total
    float* embedT   = ws + 1600;                      // 262144 floats (1 MB), guarded
    int useT = (ws_size >= (size_t)(1600 + 262144) * sizeof(float)) ? 1 : 0;

    ee_kernel<<<KDIM / 256, 256, 0, stream>>>(embed, ee);
    if (useT) transpose_e<<<256, 256, 0, stream>>>(embed, embedT);
    prep_e<<<128, 256, 0, stream>>>(embed, e_hi);
    hipMemsetAsync(wcount, 0, 4, stream);
    vq_gemm<<<NPIX / 256, 256, 0, stream>>>(x, e_hi, ee, idx_i32, worklist, wcount);
    vq_rescue<<<1024, 256, 0, stream>>>(x, embed, ee, worklist, wcount, idx_i32);
    vq_epilogue<<<NPIX / 128, 256, 0, stream>>>(x, embed, useT ? embedT : embed, useT,
                                                idx_i32, out_q, out_idx, partials);
    loss_kernel<<<1, 256, 0, stream>>>(partials, out_loss);
}

// Round 8
// 154.174 us; speedup vs baseline: 1.2595x; 1.2061x over previous
//
#include <hip/hip_runtime.h>

#define CDIM 256
#define HW   1024
#define NPIX 65536
#define KDIM 1024
#define TAU  0.5f
#define RB   4
#define SWZ(c) (((c) & 31) ^ (((c) >> 3) & 24))

using bf16x8 = __attribute__((ext_vector_type(8))) short;
using f32x4  = __attribute__((ext_vector_type(4))) float;
typedef unsigned int u32;

static __device__ __forceinline__ unsigned short f2bf(float v) {
    union { float f; unsigned u; } a; a.f = v;
    unsigned u = a.u;
    u += 0x7fffu + ((u >> 16) & 1u);   // RTN
    return (unsigned short)(u >> 16);
}

static __device__ __forceinline__ void gload_lds16(const void* g, void* s) {
    __builtin_amdgcn_global_load_lds(
        (const __attribute__((address_space(1))) u32*)g,
        (__attribute__((address_space(3))) u32*)s,
        16, 0, 0);
}

// -------- ee[k] = sum_c embed[c][k]^2 (exact fp32) --------
__global__ void ee_kernel(const float* __restrict__ embed, float* __restrict__ ee) {
    int k = blockIdx.x * 256 + threadIdx.x;
    float s = 0.f;
#pragma unroll 8
    for (int c = 0; c < CDIM; ++c) {
        float v = embed[c * KDIM + k];
        s += v * v;
    }
    ee[k] = s;
}

// -------- embedT[k][c] = embed[c][k] (fp32 transpose, 32x32 LDS tiles) --------
__global__ void transpose_e(const float* __restrict__ embed, float* __restrict__ embedT) {
    __shared__ float tl[32][33];
    const int t = threadIdx.x;
    const int j = t & 31, r = t >> 5;
    const int k0 = (blockIdx.x & 31) * 32;
    const int c0 = (blockIdx.x >> 5) * 32;
#pragma unroll
    for (int rr = 0; rr < 4; ++rr) {
        int c = r * 4 + rr;
        tl[c][j] = embed[(size_t)(c0 + c) * KDIM + k0 + j];
    }
    __syncthreads();
#pragma unroll
    for (int rr = 0; rr < 4; ++rr) {
        int k = r * 4 + rr;
        embedT[(size_t)(k0 + k) * CDIM + c0 + j] = tl[j][k];
    }
}

// -------- bf16(-2*embed) in MFMA B-fragment order --------
// frag f = ((nt*2+nh)*8 + ks)*4 + nf; lane l elem j:
//   B[k = ks*32 + (l>>4)*8 + j][n = nt*128 + (nh*4+nf)*16 + (l&15)]
__global__ void prep_e(const float* __restrict__ embed, short* __restrict__ e_hi) {
    int tid = blockIdx.x * 256 + threadIdx.x;   // 32768
    int l  = tid & 63;
    int f  = tid >> 6;            // 0..511
    int nf = f & 3;
    int ks = (f >> 2) & 7;
    int nh = (f >> 5) & 1;
    int nt = f >> 6;
    int n  = nt * 128 + (nh * 4 + nf) * 16 + (l & 15);
    int c0 = ks * 32 + (l >> 4) * 8;
    bf16x8 h8;
#pragma unroll
    for (int j = 0; j < 8; ++j)
        h8[j] = (short)f2bf(-2.0f * embed[(c0 + j) * KDIM + n]);
    *(bf16x8*)&e_hi[(size_t)tid * 8] = h8;
}

// -------- main: bf16 MFMA screen; K-split; 16 chunks of 32 codes; 2x16KB LDS --------
__launch_bounds__(256, 2)
__global__ void vq_gemm(const float* __restrict__ x, const short* __restrict__ e_hi,
                        const float* __restrict__ ee,
                        float* __restrict__ hv1, float* __restrict__ hv2,
                        int* __restrict__ hidx) {
    __shared__ short Bs[2][8192];    // 2 x 16 KB (32 codes x 256 ch each)
    const int t  = threadIdx.x;
    const int l  = t & 63;
    const int w  = t >> 6;
    const int lr = l & 15;
    const int lg = l >> 4;
    const int tile = blockIdx.x & 255;
    const int half = blockIdx.x >> 8;           // 0 or 1
    const int px0 = tile * 256 + w * 64;        // wave's 64 pixels
    const int b   = px0 >> 10;
    const int p0  = px0 & 1023;
    const float* xb = x + (size_t)b * CDIM * HW;

    // stage helper geometry: chunk c (global 0..31) = 32 codes
    //   nt = c>>2, nh = (c>>1)&1, np = c&1; slab s = w*4+i -> ks = s>>1, nfi = s&1
    //   src byte = ((nt*2+nh)*32 + ks*4 + np*2 + nfi)*1024 + l*16
    //   dst byte = (ks*2+nfi)*1024 + l*16 = s*1024 + l*16
    const int c_first = half * 16;
    {
        const int slab = w * 4;
        const char* srcb = (const char*)e_hi +
            (size_t)(((c_first >> 2) * 2 + ((c_first >> 1) & 1)) * 32 + (c_first & 1) * 2) * 1024 + l * 16;
        char* dstb = (char*)&Bs[0][0] + (size_t)slab * 1024 + l * 16;
#pragma unroll
        for (int i = 0; i < 4; ++i) {
            int s = slab + i;
            gload_lds16(srcb + (size_t)((s >> 1) * 4 + (s & 1)) * 1024, dstb + (size_t)i * 1024);
        }
    }

    // ---- load + convert A fragments (64 px x 256 ch -> 32 frags), overlaps stage ----
    bf16x8 a[4][8];
#pragma unroll
    for (int mf = 0; mf < 4; ++mf) {
#pragma unroll
        for (int ks = 0; ks < 8; ++ks) {
            const float* p = xb + (size_t)(ks * 32 + lg * 8) * HW + p0 + mf * 16 + lr;
            float v[8];
#pragma unroll
            for (int j = 0; j < 8; ++j) v[j] = p[(size_t)j * HW];
#pragma unroll
            for (int j = 0; j < 8; ++j) a[mf][ks][j] = (short)f2bf(v[j]);
        }
    }

    float minv[16], min2v[16];
    int   mini[16];
#pragma unroll
    for (int r = 0; r < 16; ++r) { minv[r] = 3.4e38f; min2v[r] = 3.4e38f; mini[r] = 0; }

    __syncthreads();   // chunk 0 staged

    for (int cc = 0; cc < 16; ++cc) {
        const int c   = c_first + cc;
        const int cur = cc & 1;
        if (cc < 15) {   // prefetch next chunk into the other buffer
            const int cn = c + 1;
            const int slab = w * 4;
            const char* srcb = (const char*)e_hi +
                (size_t)(((cn >> 2) * 2 + ((cn >> 1) & 1)) * 32 + (cn & 1) * 2) * 1024 + l * 16;
            char* dstb = (char*)&Bs[cur ^ 1][0] + (size_t)slab * 1024 + l * 16;
#pragma unroll
            for (int i = 0; i < 4; ++i) {
                int s = slab + i;
                gload_lds16(srcb + (size_t)((s >> 1) * 4 + (s & 1)) * 1024, dstb + (size_t)i * 1024);
            }
        }

        f32x4 acc[4][2];
#pragma unroll
        for (int mf = 0; mf < 4; ++mf)
#pragma unroll
            for (int nfi = 0; nfi < 2; ++nfi)
                acc[mf][nfi] = (f32x4){0.f, 0.f, 0.f, 0.f};

#pragma unroll
        for (int ks = 0; ks < 8; ++ks) {
#pragma unroll
            for (int nfi = 0; nfi < 2; ++nfi) {
                bf16x8 bh = *(const bf16x8*)&Bs[cur][((ks * 2 + nfi) * 64 + l) * 8];
#pragma unroll
                for (int mf = 0; mf < 4; ++mf)
                    acc[mf][nfi] = __builtin_amdgcn_mfma_f32_16x16x32_bf16(a[mf][ks], bh, acc[mf][nfi], 0, 0, 0);
            }
        }

        // fold chunk into running (min, argmin, second-min)
#pragma unroll
        for (int nfi = 0; nfi < 2; ++nfi) {
            const int kg = c * 32 + nfi * 16 + lr;
            const float eev = ee[kg];
#pragma unroll
            for (int mf = 0; mf < 4; ++mf)
#pragma unroll
                for (int j = 0; j < 4; ++j) {
                    const int r = mf * 4 + j;
                    float m = acc[mf][nfi][j] + eev;
                    bool lt = m < minv[r];
                    float sec = lt ? minv[r] : m;
                    minv[r] = lt ? m : minv[r];
                    mini[r] = lt ? kg : mini[r];
                    min2v[r] = fminf(min2v[r], sec);
                }
        }
        __syncthreads();   // next chunk landed + buffer swap
    }

    // ---- reduce across the 16 lanes sharing each pixel row ----
#pragma unroll
    for (int r = 0; r < 16; ++r) {
        float v1 = minv[r]; int i1 = mini[r]; float v2 = min2v[r];
#pragma unroll
        for (int mask = 1; mask < 16; mask <<= 1) {
            float ov1 = __shfl_xor(v1, mask, 64);
            int   oi1 = __shfl_xor(i1, mask, 64);
            float ov2 = __shfl_xor(v2, mask, 64);
            float vmax = fmaxf(v1, ov1);
            v2 = fminf(fminf(v2, ov2), vmax);
            bool take = (ov1 < v1) || (ov1 == v1 && oi1 < i1);
            v1 = take ? ov1 : v1;
            i1 = take ? oi1 : i1;
        }
        if (lr == 0) {
            int px = px0 + (r >> 2) * 16 + lg * 4 + (r & 3);
            int o = half * NPIX + px;
            hv1[o] = v1; hv2[o] = v2; hidx[o] = i1;
        }
    }
}

// -------- merge the two K-halves, write idx, flag near-ties --------
__global__ void merge_halves(const float* __restrict__ hv1, const float* __restrict__ hv2,
                             const int* __restrict__ hidx, int* __restrict__ idx_out,
                             int* __restrict__ worklist, int* __restrict__ wcount) {
    int px = blockIdx.x * 256 + threadIdx.x;
    float va = hv1[px],        vb = hv1[NPIX + px];
    float sa = hv2[px],        sb = hv2[NPIX + px];
    int   ia = hidx[px],       ib = hidx[NPIX + px];
    bool aw = va <= vb;            // tie -> half 0 (lower indices)
    float v1 = aw ? va : vb;
    int   i1 = aw ? ia : ib;
    float v2 = fminf(aw ? sa : sb, aw ? vb : va);
    idx_out[px] = i1;
    if (v2 - v1 < TAU) {
        int pos = atomicAdd(wcount, 1);
        worklist[pos] = px;
    }
}

// -------- exact fp32 rescore: RB px/block, thread t owns codes 4t..4t+3 --------
__launch_bounds__(256)
__global__ void vq_rescue(const float* __restrict__ x, const float* __restrict__ embed,
                          const float* __restrict__ ee,
                          const int* __restrict__ worklist, const int* __restrict__ wcount,
                          int* __restrict__ idx_out) {
    __shared__ float xs[RB][CDIM];
    __shared__ int   pxs[RB];
    __shared__ float redv[4][RB];
    __shared__ int   redi[4][RB];
    const int t  = threadIdx.x;
    const int wv = t >> 6, ln = t & 63;
    const int cnt = *wcount;
    for (int base = blockIdx.x * RB; base < cnt; base += gridDim.x * RB) {
        const int nb = min(RB, cnt - base);
        __syncthreads();
        if (t < RB) pxs[t] = worklist[base + (t < nb ? t : nb - 1)];
        __syncthreads();
#pragma unroll
        for (int i = 0; i < RB; ++i) {
            int gn = pxs[i];
            xs[i][t] = x[(size_t)(gn >> 10) * CDIM * HW + (size_t)t * HW + (gn & 1023)];
        }
        __syncthreads();

        float4 acc[RB];
#pragma unroll
        for (int i = 0; i < RB; ++i) acc[i] = make_float4(0.f, 0.f, 0.f, 0.f);
#pragma unroll 4
        for (int c = 0; c < CDIM; ++c) {
            float4 ev = *(const float4*)&embed[c * KDIM + t * 4];
#pragma unroll
            for (int i = 0; i < RB; ++i) {
                float xv = xs[i][c];
                acc[i].x = fmaf(xv, ev.x, acc[i].x);
                acc[i].y = fmaf(xv, ev.y, acc[i].y);
                acc[i].z = fmaf(xv, ev.z, acc[i].z);
                acc[i].w = fmaf(xv, ev.w, acc[i].w);
            }
        }
        const float4 eev = *(const float4*)&ee[t * 4];
#pragma unroll
        for (int i = 0; i < RB; ++i) {
            float d0 = fmaf(-2.f, acc[i].x, eev.x);
            float d1 = fmaf(-2.f, acc[i].y, eev.y);
            float d2 = fmaf(-2.f, acc[i].z, eev.z);
            float d3 = fmaf(-2.f, acc[i].w, eev.w);
            float v = d0; int ix = t * 4;
            if (d1 < v) { v = d1; ix = t * 4 + 1; }
            if (d2 < v) { v = d2; ix = t * 4 + 2; }
            if (d3 < v) { v = d3; ix = t * 4 + 3; }
#pragma unroll
            for (int mask = 1; mask < 64; mask <<= 1) {
                float ov = __shfl_xor(v, mask, 64);
                int   oi = __shfl_xor(ix, mask, 64);
                bool take = (ov < v) || (ov == v && oi < ix);
                v = take ? ov : v; ix = take ? oi : ix;
            }
            if (ln == 0) { redv[wv][i] = v; redi[wv][i] = ix; }
        }
        __syncthreads();
        if (t < nb) {
            float fv = redv[0][t]; int fi = redi[0][t];
#pragma unroll
            for (int q = 1; q < 4; ++q) {
                float v = redv[q][t]; int ix = redi[q][t];
                if (v < fv || (v == fv && ix < fi)) { fv = v; fi = ix; }
            }
            idx_out[pxs[t]] = fi;
        }
    }
}

// -------- epilogue: 128 px/block in 2 LDS passes; idx snapshot BEFORE overwrite --------
__launch_bounds__(256)
__global__ void vq_epilogue(const float* __restrict__ x, const float* __restrict__ embed,
                            const float* __restrict__ embedT, int useT,
                            const int* __restrict__ idx_in, float* __restrict__ out_q,
                            float* __restrict__ out_idx, float* __restrict__ partials) {
    __shared__ float q[16384];
    __shared__ int   idxs[128];
    __shared__ float lred[4];
    const int t = threadIdx.x;
    const int w = t >> 6, l = t & 63;
    const int n0 = blockIdx.x * 128;
    const int b  = n0 >> 10;

    if (t < 128) idxs[t] = idx_in[n0 + t];
    __syncthreads();
    if (t < 128) out_idx[n0 + t] = (float)idxs[t];

    const int j  = t >> 2;
    const int qd = t & 3;
    float lsum = 0.f;

#pragma unroll
    for (int pass = 0; pass < 2; ++pass) {
        const int myidx = idxs[pass * 64 + j];
        if (useT) {
            const float4* src4 = (const float4*)embedT + (size_t)myidx * 64;
#pragma unroll
            for (int i = 0; i < 16; ++i) {
                float4 v = src4[qd * 16 + i];
                int c = qd * 64 + i * 4;
                q[(c + 0) * 64 + (j ^ SWZ(c + 0))] = v.x;
                q[(c + 1) * 64 + (j ^ SWZ(c + 1))] = v.y;
                q[(c + 2) * 64 + (j ^ SWZ(c + 2))] = v.z;
                q[(c + 3) * 64 + (j ^ SWZ(c + 3))] = v.w;
            }
        } else {
#pragma unroll 4
            for (int i = 0; i < 64; ++i) {
                int c = qd * 64 + i;
                q[c * 64 + (j ^ SWZ(c))] = embed[(size_t)c * KDIM + myidx];
            }
        }
        __syncthreads();

        const int p0 = (n0 & 1023) + pass * 64;
        const size_t xbase = (size_t)b * CDIM * HW + p0;
#pragma unroll 8
        for (int ci = 0; ci < 64; ++ci) {
            int c = w * 64 + ci;
            float qv = q[c * 64 + (l ^ SWZ(c))];
            float xv = x[xbase + (size_t)c * HW + l];
            out_q[xbase + (size_t)c * HW + l] = qv;
            float d = qv - xv;
            lsum = fmaf(d, d, lsum);
        }
        __syncthreads();
    }

#pragma unroll
    for (int off = 32; off > 0; off >>= 1)
        lsum += __shfl_down(lsum, off, 64);
    if (l == 0) lred[w] = lsum;
    __syncthreads();
    if (t == 0)
        partials[blockIdx.x] = (lred[0] + lred[1]) + (lred[2] + lred[3]);
}

__global__ void loss_kernel(const float* __restrict__ partials, float* __restrict__ out_loss) {
    __shared__ float s[256];
    s[threadIdx.x] = partials[threadIdx.x] + partials[threadIdx.x + 256];
    __syncthreads();
    for (int off = 128; off > 0; off >>= 1) {
        if (threadIdx.x < off) s[threadIdx.x] += s[threadIdx.x + off];
        __syncthreads();
    }
    if (threadIdx.x == 0)
        out_loss[0] = 1.25f * s[0] / 16777216.0f;
}

extern "C" void kernel_launch(void* const* d_in, const int* in_sizes, int n_in,
                              void* d_out, int out_size, void* d_ws, size_t ws_size,
                              hipStream_t stream) {
    const float* x     = (const float*)d_in[0];
    const float* embed = (const float*)d_in[1];
    float* out_q    = (float*)d_out;
    float* out_loss = out_q + (size_t)NPIX * CDIM;
    float* out_idx  = out_loss + 1;
    int*   idx_i32  = (int*)out_idx;

    // scratch inside out_q region (all consumed before epilogue writes)
    short* e_hi     = (short*)out_q;                  // 512 KB
    int*   worklist = (int*)(out_q + 131072);         // 256 KB
    float* hv1      = out_q + 196608;                 // 2 x 64K floats
    float* hv2      = out_q + 327680;
    int*   hidx     = (int*)(out_q + 458752);

    // d_ws: proven-safe 6.4 KB budget; embedT only behind ws_size guard
    float* ws       = (float*)d_ws;
    float* ee       = ws;                             // 1024 floats
    int*   wcount   = (int*)(ws + 1024);
    float* partials = ws + 1088;                      // 512 floats
    float* embedT   = ws + 1600;                      // 262144 floats (1 MB), guarded
    int useT = (ws_size >= (size_t)(1600 + 262144) * sizeof(float)) ? 1 : 0;

    ee_kernel<<<KDIM / 256, 256, 0, stream>>>(embed, ee);
    if (useT) transpose_e<<<256, 256, 0, stream>>>(embed, embedT);
    prep_e<<<128, 256, 0, stream>>>(embed, e_hi);
    hipMemsetAsync(wcount, 0, 4, stream);
    vq_gemm<<<512, 256, 0, stream>>>(x, e_hi, ee, hv1, hv2, hidx);
    merge_halves<<<NPIX / 256, 256, 0, stream>>>(hv1, hv2, hidx, idx_i32, worklist, wcount);
    vq_rescue<<<1024, 256, 0, stream>>>(x, embed, ee, worklist, wcount, idx_i32);
    vq_epilogue<<<NPIX / 128, 256, 0, stream>>>(x, embed, useT ? embedT : embed, useT,
                                                idx_i32, out_q, out_idx, partials);
    loss_kernel<<<1, 256, 0, stream>>>(partials, out_loss);
}